// Round 1
// baseline (397.693 us; speedup 1.0000x reference)
//
#include <hip/hip_runtime.h>
#include <hip/hip_bf16.h>

// Sizes
#define BB 16
#define LL 4096
#define CC 512
#define GG 8
#define CG_ 64
#define NG 128   // B*G
#define IC1 68   // CG+WD
#define OC1 64
#define OC2 32

// ---------------- prep: transpose weights, corr precompute ----------------
__global__ __launch_bounds__(256) void k_prep(const float* __restrict__ x,
    const float* __restrict__ w1, const float* __restrict__ w2,
    const float* __restrict__ gate,
    float* __restrict__ w1t, float* __restrict__ w2t, float* __restrict__ corr)
{
    int idx = blockIdx.x * 256 + threadIdx.x;
    if (idx < 13056) {                     // w1t[(ic*4+ocg)*48 + k*16+oc']
        int ic = idx / 192; int r = idx - ic * 192;
        int ocg = r / 48;   int j = r - ocg * 48;
        int k = j >> 4;     int ocp = j & 15;
        int oc = ocg * 16 + ocp;
        w1t[idx] = w1[(oc * IC1 + ic) * 3 + k];
    } else if (idx < 19200) {              // w2t[(ic*4+ocg)*24 + k*8+oc']
        int i2 = idx - 13056;
        int ic = i2 / 96;  int r = i2 - ic * 96;
        int ocg = r / 24;  int j = r - ocg * 24;
        int k = j >> 3;    int ocp = j & 7;
        int oc = ocg * 8 + ocp;
        w2t[i2] = w2[(oc * OC1 + ic) * 3 + k];
    } else if (idx < 27392) {              // corr[b*512+ch]
        int i3 = idx - 19200;
        int b = i3 >> 9; int ch = i3 & 511;
        float tg = tanhf(gate[0]);
        corr[i3] = tg * 0.5f *
            (x[((size_t)(b * LL + 2047)) * CC + ch] +
             x[((size_t)(b * LL + 2048)) * CC + ch]);
    }
}

// ---------------- K1: conv1 + bias -> h1 (bf16), group partial sums -------
__global__ __launch_bounds__(256) void k1_conv1(const float* __restrict__ x,
    const float* __restrict__ xe, const float* __restrict__ b1,
    const float* __restrict__ w1t, __hip_bfloat16* __restrict__ h1,
    float* __restrict__ part)
{
    __shared__ float pin[IC1 * 67];        // [ic][li], stride 67 (odd -> no conflicts)
    const int n = blockIdx.y, lt = blockIdx.x;
    const int b = n >> 3, g = n & 7, be = n & 15;
    const int l0 = lt * 64;
    const int t = threadIdx.x;

    for (int pos = t; pos < 66 * IC1; pos += 256) {
        int li = pos / IC1, ch = pos - li * IC1;
        int l = l0 - 1 + li;
        float v = 0.f;
        if (l >= 0 && l < LL) {
            v = (ch < 64) ? x[((size_t)(b * LL + l)) * CC + g * 64 + ch]
                          : xe[(be * LL + l) * 4 + (ch - 64)];
        }
        pin[ch * 67 + li] = v;
    }
    __syncthreads();

    const int lane = t & 63;
    const int w = __builtin_amdgcn_readfirstlane(t >> 6);  // oc-group == GN group
    float acc[16];
#pragma unroll
    for (int j = 0; j < 16; ++j) acc[j] = b1[w * 16 + j];

    for (int ic = 0; ic < IC1; ++ic) {
        float i0 = pin[ic * 67 + lane];
        float i1 = pin[ic * 67 + lane + 1];
        float i2 = pin[ic * 67 + lane + 2];
        const float* wp = w1t + (ic * 4 + w) * 48;   // uniform -> s_load
#pragma unroll
        for (int j = 0; j < 16; ++j) {
            acc[j] = fmaf(wp[j],      i0, acc[j]);
            acc[j] = fmaf(wp[16 + j], i1, acc[j]);
            acc[j] = fmaf(wp[32 + j], i2, acc[j]);
        }
    }

    const int l = l0 + lane;
    float s1 = 0.f, s2 = 0.f;
#pragma unroll
    for (int j = 0; j < 16; ++j) {
        s1 += acc[j]; s2 += acc[j] * acc[j];
        int oc = w * 16 + j;
        h1[((size_t)(n * 64 + oc)) * LL + l] = __float2bfloat16(acc[j]);
    }
#pragma unroll
    for (int off = 32; off > 0; off >>= 1) {
        s1 += __shfl_down(s1, off, 64);
        s2 += __shfl_down(s2, off, 64);
    }
    if (lane == 0) {
        part[((n * 4 + w) * 64 + lt) * 2 + 0] = s1;
        part[((n * 4 + w) * 64 + lt) * 2 + 1] = s2;
    }
}

// ---------------- K2: finalize mean / invstd ------------------------------
__global__ __launch_bounds__(512) void k2_stats(const float* __restrict__ part,
                                                float* __restrict__ stats)
{
    int tid = threadIdx.x;                 // 512 = 128 n * 4 groups
    if (tid >= 512) return;
    float s1 = 0.f, s2 = 0.f;
    for (int lt = 0; lt < 64; ++lt) {
        s1 += part[(tid * 64 + lt) * 2 + 0];
        s2 += part[(tid * 64 + lt) * 2 + 1];
    }
    float mean = s1 * (1.0f / 65536.0f);
    float var  = s2 * (1.0f / 65536.0f) - mean * mean;
    stats[tid * 2 + 0] = mean;
    stats[tid * 2 + 1] = 1.0f / sqrtf(var + 1e-5f);
}

// ---------------- K3: GN+GELU -> conv2+GELU -> conv3 -> tanh*10 -----------
// tile of 126 outputs; h2 computed at 128 positions (2 exact wave passes)
__global__ __launch_bounds__(256) void k3_rest(const __hip_bfloat16* __restrict__ h1,
    const float* __restrict__ stats, const float* __restrict__ gn_g,
    const float* __restrict__ gn_b, const float* __restrict__ b2,
    const float* __restrict__ w2t, const float* __restrict__ w3,
    float* __restrict__ offs)
{
    __shared__ float h1s[64 * 131];        // [ch][li], li in [0,130)
    __shared__ float h2s[32 * 129];        // [oc][p],  p  in [0,128)
    const int n = blockIdx.y, lt = blockIdx.x;
    const int l0 = lt * 126;
    const int t = threadIdx.x;

    for (int pos = t; pos < 64 * 130; pos += 256) {
        int ch = pos / 130, li = pos - ch * 130;
        int l = l0 - 2 + li;
        float v = 0.f;
        if (l >= 0 && l < LL) {
            float hv = __bfloat162float(h1[((size_t)(n * 64 + ch)) * LL + l]);
            int gi = (n * 4 + (ch >> 4)) * 2;
            float xn = (hv - stats[gi]) * stats[gi + 1] * gn_g[ch] + gn_b[ch];
            v = 0.5f * xn * (1.0f + erff(xn * 0.70710678118654752f));
        }
        h1s[ch * 131 + li] = v;
    }
    __syncthreads();

    const int lane = t & 63;
    const int w = __builtin_amdgcn_readfirstlane(t >> 6);
#pragma unroll
    for (int pass = 0; pass < 2; ++pass) {
        int p = lane + pass * 64;          // h2 position, l = l0-1+p
        int l = l0 - 1 + p;
        float acc[8];
        if (l >= 0 && l < LL) {
#pragma unroll
            for (int j = 0; j < 8; ++j) acc[j] = b2[w * 8 + j];
            for (int ic = 0; ic < 64; ++ic) {
                float i0 = h1s[ic * 131 + p];
                float i1 = h1s[ic * 131 + p + 1];
                float i2 = h1s[ic * 131 + p + 2];
                const float* wp = w2t + (ic * 4 + w) * 24;  // uniform -> s_load
#pragma unroll
                for (int j = 0; j < 8; ++j) {
                    acc[j] = fmaf(wp[j],      i0, acc[j]);
                    acc[j] = fmaf(wp[8 + j],  i1, acc[j]);
                    acc[j] = fmaf(wp[16 + j], i2, acc[j]);
                }
            }
#pragma unroll
            for (int j = 0; j < 8; ++j)
                acc[j] = 0.5f * acc[j] * (1.0f + erff(acc[j] * 0.70710678118654752f));
        } else {
#pragma unroll
            for (int j = 0; j < 8; ++j) acc[j] = 0.f;
        }
#pragma unroll
        for (int j = 0; j < 8; ++j) h2s[(w * 8 + j) * 129 + p] = acc[j];
    }
    __syncthreads();

    for (int q = t; q < 126; q += 256) {
        int l = l0 + q;
        if (l >= LL) break;
        float acc = 0.f;
#pragma unroll
        for (int ic = 0; ic < 32; ++ic) {
            acc = fmaf(w3[ic * 3 + 0], h2s[ic * 129 + q],     acc);
            acc = fmaf(w3[ic * 3 + 1], h2s[ic * 129 + q + 1], acc);
            acc = fmaf(w3[ic * 3 + 2], h2s[ic * 129 + q + 2], acc);
        }
        offs[n * LL + l] = tanhf(acc) * 10.0f;
    }
}

// ---------------- K0: out0 = x + corr[b,ch] (float4) ----------------------
__global__ __launch_bounds__(256) void k0_out(const float* __restrict__ x,
    const float* __restrict__ corr, float* __restrict__ out)
{
    const size_t total4 = (size_t)BB * LL * CC / 4;  // 8388608
    size_t i = (size_t)blockIdx.x * blockDim.x + threadIdx.x;
    size_t stride = (size_t)gridDim.x * blockDim.x;
    for (size_t idx = i; idx < total4; idx += stride) {
        float4 xv = ((const float4*)x)[idx];
        int cidx = (int)((idx >> 19) * 128 + (idx & 127)); // b*128 + (flat%512)/4
        float4 cv = ((const float4*)corr)[cidx];
        float4 o;
        o.x = xv.x + cv.x; o.y = xv.y + cv.y;
        o.z = xv.z + cv.z; o.w = xv.w + cv.w;
        ((float4*)out)[idx] = o;
    }
}

extern "C" void kernel_launch(void* const* d_in, const int* in_sizes, int n_in,
                              void* d_out, int out_size, void* d_ws, size_t ws_size,
                              hipStream_t stream)
{
    const float* x    = (const float*)d_in[0];
    const float* xext = (const float*)d_in[1];
    const float* w1   = (const float*)d_in[2];
    const float* b1   = (const float*)d_in[3];
    const float* gng  = (const float*)d_in[4];
    const float* gnb  = (const float*)d_in[5];
    const float* w2   = (const float*)d_in[6];
    const float* b2   = (const float*)d_in[7];
    const float* w3   = (const float*)d_in[8];
    const float* gate = (const float*)d_in[9];

    float* out  = (float*)d_out;
    float* offs = out + (size_t)BB * LL * CC;        // 33,554,432

    char* ws = (char*)d_ws;
    __hip_bfloat16* h1 = (__hip_bfloat16*)(ws);      // 67,108,864 B
    float* part  = (float*)(ws + 67108864);          // 262,144 B
    float* stats = (float*)(ws + 67371008);          // 4,096 B
    float* w1t   = (float*)(ws + 67375104);          // 52,224 B
    float* w2t   = (float*)(ws + 67427328);          // 24,576 B
    float* corr  = (float*)(ws + 67451904);          // 32,768 B

    k_prep<<<107, 256, 0, stream>>>(x, w1, w2, gate, w1t, w2t, corr);
    dim3 g1(64, NG);
    k1_conv1<<<g1, 256, 0, stream>>>(x, xext, b1, w1t, h1, part);
    k2_stats<<<1, 512, 0, stream>>>(part, stats);
    dim3 g3(33, NG);
    k3_rest<<<g3, 256, 0, stream>>>(h1, stats, gng, gnb, b2, w2t, w3, offs);
    k0_out<<<4096, 256, 0, stream>>>(x, corr, out);
}

// Round 2
// 194.518 us; speedup vs baseline: 2.0445x; 2.0445x over previous
//
#include <hip/hip_runtime.h>
#include <hip/hip_bf16.h>

#define BB 16
#define LL 4096
#define CC 512
#define NG 128   // B*G
#define IC1 68
#define OC1 64
#define OC2 32

typedef short short8 __attribute__((ext_vector_type(8)));
typedef float f32x4 __attribute__((ext_vector_type(4)));

__device__ inline ushort f2b(float f) {
    __hip_bfloat16 h = __float2bfloat16(f);
    return *reinterpret_cast<ushort*>(&h);
}
__device__ inline float b2f(ushort u) {
    __hip_bfloat16 h;
    *reinterpret_cast<ushort*>(&h) = u;
    return __bfloat162float(h);
}
__device__ inline float fast_tanh(float y) {
    float e = __expf(2.0f * y);
    return 1.0f - 2.0f / (e + 1.0f);
}
__device__ inline float fast_gelu(float x) {
    float y = x * (0.7978845608f + 0.0356774081f * x * x);
    return 0.5f * x * (1.0f + fast_tanh(y));
}

// ---------------- prep: bf16 weights (padded), corr ----------------
__global__ __launch_bounds__(256) void k_prep(const float* __restrict__ x,
    const float* __restrict__ w1, const float* __restrict__ w2,
    const float* __restrict__ gate,
    ushort* __restrict__ w1b, ushort* __restrict__ w2b, float* __restrict__ corr)
{
    int idx = blockIdx.x * 256 + threadIdx.x;
    if (idx < 18432) {                       // w1b[k][oc][icp<96]
        int k = idx / 6144; int r = idx - k * 6144;
        int oc = r / 96;    int icp = r - oc * 96;
        float v = (icp < IC1) ? w1[(oc * IC1 + icp) * 3 + k] : 0.0f;
        w1b[idx] = f2b(v);
    } else if (idx < 24576) {                // w2b[k][oc][ic<64]
        int j = idx - 18432;
        int k = j / 2048; int r = j - k * 2048;
        int oc = r / 64;  int ic = r - oc * 64;
        w2b[j] = f2b(w2[(oc * OC1 + ic) * 3 + k]);
    } else if (idx < 32768) {                // corr[b*512+ch]
        int i3 = idx - 24576;
        int b = i3 >> 9; int ch = i3 & 511;
        float tg = tanhf(gate[0]);
        corr[i3] = tg * 0.5f *
            (x[((size_t)(b * LL + 2047)) * CC + ch] +
             x[((size_t)(b * LL + 2048)) * CC + ch]);
    }
}

// ---------------- K1: conv1 via MFMA, bias+sums in epilogue ----------------
// block: 128 l positions, 4 waves: w&1 = oc-half, w>>1 = l-half
#define K1_ROWS 130
#define K1_STR  104   // ushorts per row (208 B = 13 x 16B)
__global__ __launch_bounds__(256) void k1_conv1(const float* __restrict__ x,
    const float* __restrict__ xe, const float* __restrict__ b1,
    const ushort* __restrict__ w1b, ushort* __restrict__ h1,
    float* __restrict__ part)
{
    __shared__ ushort pin[K1_ROWS * K1_STR];   // 27040 B
    const int n = blockIdx.y, lt = blockIdx.x;
    const int b = n >> 3, g = n & 7, be = n & 15;
    const int l0 = lt * 128;
    const int t = threadIdx.x;

    // stage x -> pin[li][0..63] as bf16 (li <-> l = l0-1+li)
    for (int pos = t; pos < K1_ROWS * 16; pos += 256) {
        int li = pos >> 4, q = pos & 15;
        int l = l0 - 1 + li;
        float4 v = make_float4(0.f, 0.f, 0.f, 0.f);
        if (l >= 0 && l < LL)
            v = *(const float4*)&x[((size_t)(b * LL + l)) * CC + g * 64 + q * 4];
        uint lo = (uint)f2b(v.x) | ((uint)f2b(v.y) << 16);
        uint hi = (uint)f2b(v.z) | ((uint)f2b(v.w) << 16);
        *(uint2*)&pin[li * K1_STR + q * 4] = make_uint2(lo, hi);
    }
    // stage xe -> pin[li][64..67]
    for (int li = t; li < K1_ROWS; li += 256) {
        int l = l0 - 1 + li;
        float4 v = make_float4(0.f, 0.f, 0.f, 0.f);
        if (l >= 0 && l < LL)
            v = *(const float4*)&xe[(size_t)(be * LL + l) * 4];
        uint lo = (uint)f2b(v.x) | ((uint)f2b(v.y) << 16);
        uint hi = (uint)f2b(v.z) | ((uint)f2b(v.w) << 16);
        *(uint2*)&pin[li * K1_STR + 64] = make_uint2(lo, hi);
    }
    // zero pin[li][68..95]
    {
        uint* pz = (uint*)pin;
        for (int pos = t; pos < K1_ROWS * 14; pos += 256) {
            int li = pos / 14, j = pos - li * 14;
            pz[li * 52 + 34 + j] = 0u;
        }
    }
    __syncthreads();

    const int lane = t & 63;
    const int w = t >> 6;
    const int och = w & 1, lh = w >> 1;
    const int m = lane & 15, h = lane >> 4;

    // A fragments: weights, 2 oc-tiles x (3 taps x 3 chunks)
    short8 fa[2][9];
#pragma unroll
    for (int mi = 0; mi < 2; ++mi)
#pragma unroll
        for (int k = 0; k < 3; ++k)
#pragma unroll
            for (int c = 0; c < 3; ++c)
                fa[mi][k * 3 + c] = *(const short8*)&w1b[
                    (size_t)(k * 64 + och * 32 + mi * 16 + m) * 96 + c * 32 + h * 8];

    f32x4 acc[2][4] = {};
#pragma unroll
    for (int tt = 0; tt < 4; ++tt) {
        const int rowbase = lh * 64 + tt * 16 + m;
#pragma unroll
        for (int k = 0; k < 3; ++k) {
#pragma unroll
            for (int c = 0; c < 3; ++c) {
                short8 fb = *(const short8*)&pin[(rowbase + k) * K1_STR + c * 32 + h * 8];
                acc[0][tt] = __builtin_amdgcn_mfma_f32_16x16x32_bf16(fa[0][k * 3 + c], fb, acc[0][tt], 0, 0, 0);
                acc[1][tt] = __builtin_amdgcn_mfma_f32_16x16x32_bf16(fa[1][k * 3 + c], fb, acc[1][tt], 0, 0, 0);
            }
        }
    }

    // epilogue: bias, bf16 store, group sums
#pragma unroll
    for (int mi = 0; mi < 2; ++mi) {
        float bias[4];
#pragma unroll
        for (int r = 0; r < 4; ++r)
            bias[r] = b1[och * 32 + mi * 16 + h * 4 + r];
        float s1 = 0.f, s2 = 0.f;
#pragma unroll
        for (int tt = 0; tt < 4; ++tt) {
#pragma unroll
            for (int r = 0; r < 4; ++r) {
                float v = acc[mi][tt][r] + bias[r];
                s1 += v; s2 += v * v;
                int oc = och * 32 + mi * 16 + h * 4 + r;
                int l = l0 + lh * 64 + tt * 16 + m;
                h1[((size_t)(n * 64 + oc)) * LL + l] = f2b(v);
            }
        }
#pragma unroll
        for (int off = 32; off > 0; off >>= 1) {
            s1 += __shfl_down(s1, off, 64);
            s2 += __shfl_down(s2, off, 64);
        }
        if (lane == 0) {
            int gidx = och * 2 + mi;
            part[(((size_t)n * 4 + gidx) * 64 + lt * 2 + lh) * 2 + 0] = s1;
            part[(((size_t)n * 4 + gidx) * 64 + lt * 2 + lh) * 2 + 1] = s2;
        }
    }
}

// ---------------- K2: finalize mean / invstd ------------------------------
__global__ __launch_bounds__(512) void k2_stats(const float* __restrict__ part,
                                                float* __restrict__ stats)
{
    int tid = threadIdx.x;                 // 512 = 128 n * 4 groups
    float s1 = 0.f, s2 = 0.f;
    for (int j = 0; j < 64; ++j) {
        s1 += part[((size_t)tid * 64 + j) * 2 + 0];
        s2 += part[((size_t)tid * 64 + j) * 2 + 1];
    }
    float mean = s1 * (1.0f / 65536.0f);
    float var  = s2 * (1.0f / 65536.0f) - mean * mean;
    stats[tid * 2 + 0] = mean;
    stats[tid * 2 + 1] = 1.0f / sqrtf(var + 1e-5f);
}

// ---------------- K3: GN+GELU -> conv2(MFMA)+GELU -> conv3 -> tanh*10 -----
// tile: 126 outputs, 128 h2 positions (j=0..127 <-> l=l0-1+j)
#define K3_ROWS 130
#define K3_STR  72    // ushorts per row (144 B = 9 x 16B)
#define H2_STR  132
__global__ __launch_bounds__(256) void k3_rest(const ushort* __restrict__ h1,
    const float* __restrict__ stats, const float* __restrict__ gn_g,
    const float* __restrict__ gn_b, const float* __restrict__ b2,
    const ushort* __restrict__ w2b, const float* __restrict__ w3,
    float* __restrict__ offs)
{
    __shared__ ushort p2[K3_ROWS * K3_STR];   // 18720 B
    __shared__ float h2s[OC2 * H2_STR];       // 16896 B
    const int n = blockIdx.y, lt = blockIdx.x;
    const int l0 = lt * 126;
    const int t = threadIdx.x;

    // stage GELU(GN(h1)) -> p2[li][ch], li <-> l = l0-2+li, zero outside
    const int base = (l0 - 2) & ~7;
    for (int pos = t; pos < 64 * 18; pos += 256) {
        int ch = pos / 18, s = pos - ch * 18;
        int ls = base + s * 8;
        ushort u8[8];
        if (ls >= 0 && ls + 8 <= LL) {
            *(uint4*)u8 = *(const uint4*)&h1[((size_t)(n * 64 + ch)) * LL + ls];
        } else {
#pragma unroll
            for (int j = 0; j < 8; ++j) {
                int l = ls + j;
                u8[j] = (l >= 0 && l < LL) ? h1[((size_t)(n * 64 + ch)) * LL + l] : (ushort)0;
            }
        }
        int gi = (n * 4 + (ch >> 4)) * 2;
        float mean = stats[gi], istd = stats[gi + 1];
        float ga = gn_g[ch], bb = gn_b[ch];
#pragma unroll
        for (int j = 0; j < 8; ++j) {
            int l = ls + j;
            int li = l - (l0 - 2);
            if (li < 0 || li >= K3_ROWS) continue;
            float v = 0.f;
            if (l >= 0 && l < LL) {
                float xn = (b2f(u8[j]) - mean) * istd * ga + bb;
                v = fast_gelu(xn);
            }
            p2[li * K3_STR + ch] = f2b(v);
        }
    }
    __syncthreads();

    const int lane = t & 63;
    const int w = t >> 6;
    const int m = lane & 15, h = lane >> 4;

    // A fragments: 2 oc-tiles x (3 taps x 2 chunks)
    short8 fa[2][6];
#pragma unroll
    for (int mi = 0; mi < 2; ++mi)
#pragma unroll
        for (int k = 0; k < 3; ++k)
#pragma unroll
            for (int c = 0; c < 2; ++c)
                fa[mi][k * 2 + c] = *(const short8*)&w2b[
                    (size_t)(k * 32 + mi * 16 + m) * 64 + c * 32 + h * 8];

    float bias2[2][4];
#pragma unroll
    for (int mi = 0; mi < 2; ++mi)
#pragma unroll
        for (int r = 0; r < 4; ++r)
            bias2[mi][r] = b2[mi * 16 + h * 4 + r];

    f32x4 acc[2][2] = {};
#pragma unroll
    for (int u = 0; u < 2; ++u) {
        const int jb = (w * 2 + u) * 16 + m;     // col j
#pragma unroll
        for (int k = 0; k < 3; ++k) {
#pragma unroll
            for (int c = 0; c < 2; ++c) {
                short8 fb = *(const short8*)&p2[(jb + k) * K3_STR + c * 32 + h * 8];
                acc[0][u] = __builtin_amdgcn_mfma_f32_16x16x32_bf16(fa[0][k * 2 + c], fb, acc[0][u], 0, 0, 0);
                acc[1][u] = __builtin_amdgcn_mfma_f32_16x16x32_bf16(fa[1][k * 2 + c], fb, acc[1][u], 0, 0, 0);
            }
        }
    }
    // h2 = GELU(acc + b2) -> h2s[oc][j], zero for l outside
#pragma unroll
    for (int mi = 0; mi < 2; ++mi) {
#pragma unroll
        for (int u = 0; u < 2; ++u) {
            int j = (w * 2 + u) * 16 + m;
            int lj = l0 - 1 + j;
#pragma unroll
            for (int r = 0; r < 4; ++r) {
                int oc = mi * 16 + h * 4 + r;
                float v = 0.f;
                if (lj >= 0 && lj < LL)
                    v = fast_gelu(acc[mi][u][r] + bias2[mi][r]);
                h2s[oc * H2_STR + j] = v;
            }
        }
    }
    __syncthreads();

    // conv3 + tanh*10
    for (int q = t; q < 126; q += 256) {
        int l = l0 + q;
        if (l >= LL) break;
        float a = 0.f;
#pragma unroll
        for (int ic = 0; ic < OC2; ++ic) {
            a = fmaf(w3[ic * 3 + 0], h2s[ic * H2_STR + q],     a);
            a = fmaf(w3[ic * 3 + 1], h2s[ic * H2_STR + q + 1], a);
            a = fmaf(w3[ic * 3 + 2], h2s[ic * H2_STR + q + 2], a);
        }
        offs[(size_t)n * LL + l] = fast_tanh(a) * 10.0f;
    }
}

// ---------------- K0: out0 = x + corr[b,ch] (float4) ----------------------
__global__ __launch_bounds__(256) void k0_out(const float* __restrict__ x,
    const float* __restrict__ corr, float* __restrict__ out)
{
    const size_t total4 = (size_t)BB * LL * CC / 4;  // 8388608
    size_t i = (size_t)blockIdx.x * blockDim.x + threadIdx.x;
    size_t stride = (size_t)gridDim.x * blockDim.x;
    for (size_t idx = i; idx < total4; idx += stride) {
        float4 xv = ((const float4*)x)[idx];
        int cidx = (int)((idx >> 19) * 128 + (idx & 127));
        float4 cv = ((const float4*)corr)[cidx];
        float4 o;
        o.x = xv.x + cv.x; o.y = xv.y + cv.y;
        o.z = xv.z + cv.z; o.w = xv.w + cv.w;
        ((float4*)out)[idx] = o;
    }
}

extern "C" void kernel_launch(void* const* d_in, const int* in_sizes, int n_in,
                              void* d_out, int out_size, void* d_ws, size_t ws_size,
                              hipStream_t stream)
{
    const float* x    = (const float*)d_in[0];
    const float* xext = (const float*)d_in[1];
    const float* w1   = (const float*)d_in[2];
    const float* b1   = (const float*)d_in[3];
    const float* gng  = (const float*)d_in[4];
    const float* gnb  = (const float*)d_in[5];
    const float* w2   = (const float*)d_in[6];
    const float* b2   = (const float*)d_in[7];
    const float* w3   = (const float*)d_in[8];
    const float* gate = (const float*)d_in[9];

    float* out  = (float*)d_out;
    float* offs = out + (size_t)BB * LL * CC;        // 33,554,432

    char* ws = (char*)d_ws;
    ushort* h1  = (ushort*)(ws);                     // 67,108,864 B
    float* part = (float*)(ws + 67108864);           // 262,144 B
    float* stats= (float*)(ws + 67371008);           // 4,096 B
    ushort* w1b = (ushort*)(ws + 67375104);          // 36,864 B
    ushort* w2b = (ushort*)(ws + 67411968);          // 12,288 B
    float* corr = (float*)(ws + 67424256);           // 32,768 B

    k_prep<<<128, 256, 0, stream>>>(x, w1, w2, gate, w1b, w2b, corr);
    dim3 g1(32, NG);
    k1_conv1<<<g1, 256, 0, stream>>>(x, xext, b1, w1b, h1, part);
    k2_stats<<<1, 512, 0, stream>>>(part, stats);
    dim3 g3(33, NG);
    k3_rest<<<g3, 256, 0, stream>>>(h1, stats, gng, gnb, b2, w2b, w3, offs);
    k0_out<<<4096, 256, 0, stream>>>(x, corr, out);
}

// Round 3
// 156.089 us; speedup vs baseline: 2.5479x; 1.2462x over previous
//
#include <hip/hip_runtime.h>
#include <hip/hip_bf16.h>

#define BB 16
#define LL 4096
#define CC 512
#define NG 128   // B*G
#define IC1 68
#define OC1 64
#define OC2 32

typedef short short8 __attribute__((ext_vector_type(8)));
typedef float f32x4 __attribute__((ext_vector_type(4)));

__device__ inline ushort f2b(float f) {
    __hip_bfloat16 h = __float2bfloat16(f);
    return *reinterpret_cast<ushort*>(&h);
}
__device__ inline float b2f(ushort u) {
    __hip_bfloat16 h;
    *reinterpret_cast<ushort*>(&h) = u;
    return __bfloat162float(h);
}
__device__ inline float fast_tanh(float y) {
    float e = __expf(2.0f * y);
    return 1.0f - 2.0f / (e + 1.0f);
}
__device__ inline float fast_gelu(float x) {
    float y = x * (0.7978845608f + 0.0356774081f * x * x);
    return 0.5f * x * (1.0f + fast_tanh(y));
}

// ---------------- prep: bf16 weights (padded), corr ----------------
__global__ __launch_bounds__(256) void k_prep(const float* __restrict__ x,
    const float* __restrict__ w1, const float* __restrict__ w2,
    const float* __restrict__ gate,
    ushort* __restrict__ w1b, ushort* __restrict__ w2b, float* __restrict__ corr)
{
    int idx = blockIdx.x * 256 + threadIdx.x;
    if (idx < 18432) {                       // w1b[k][oc][icp<96]
        int k = idx / 6144; int r = idx - k * 6144;
        int oc = r / 96;    int icp = r - oc * 96;
        float v = (icp < IC1) ? w1[(oc * IC1 + icp) * 3 + k] : 0.0f;
        w1b[idx] = f2b(v);
    } else if (idx < 24576) {                // w2b[k][oc][ic<64]
        int j = idx - 18432;
        int k = j / 2048; int r = j - k * 2048;
        int oc = r / 64;  int ic = r - oc * 64;
        w2b[j] = f2b(w2[(oc * OC1 + ic) * 3 + k]);
    } else if (idx < 32768) {                // corr[b*512+ch]
        int i3 = idx - 24576;
        int b = i3 >> 9; int ch = i3 & 511;
        float tg = tanhf(gate[0]);
        corr[i3] = tg * 0.5f *
            (x[((size_t)(b * LL + 2047)) * CC + ch] +
             x[((size_t)(b * LL + 2048)) * CC + ch]);
    }
}

// ---------------- K1: conv1 via MFMA + fused out-write ----------------
// block: 128 l positions, 4 waves: w&1 = oc-half, w>>1 = l-half
#define K1_ROWS 130
#define K1_STR  104   // ushorts per row (208 B = 13 x 16B)
__global__ __launch_bounds__(256) void k1_conv1(const float* __restrict__ x,
    const float* __restrict__ xe, const float* __restrict__ b1,
    const ushort* __restrict__ w1b, const float* __restrict__ corr,
    ushort* __restrict__ h1, float* __restrict__ part, float* __restrict__ out)
{
    __shared__ ushort pin[K1_ROWS * K1_STR];   // 27040 B
    const int n = blockIdx.y, lt = blockIdx.x;
    const int b = n >> 3, g = n & 7, be = n & 15;
    const int l0 = lt * 128;
    const int t = threadIdx.x;

    // stage x -> pin[li][0..63] bf16, and fused out = x + corr
    {
        const int q = t & 15;                  // constant per thread (256 % 16 == 0)
        const float4 corrv = *(const float4*)&corr[(b << 9) + g * 64 + q * 4];
        for (int pos = t; pos < K1_ROWS * 16; pos += 256) {
            int li = pos >> 4;
            int l = l0 - 1 + li;
            float4 v = make_float4(0.f, 0.f, 0.f, 0.f);
            if (l >= 0 && l < LL) {
                v = *(const float4*)&x[((size_t)(b * LL + l)) * CC + g * 64 + q * 4];
                if (li >= 1 && li <= 128) {    // each l in [l0,l0+128) exactly once
                    float4 o;
                    o.x = v.x + corrv.x; o.y = v.y + corrv.y;
                    o.z = v.z + corrv.z; o.w = v.w + corrv.w;
                    *(float4*)&out[((size_t)(b * LL + l)) * CC + g * 64 + q * 4] = o;
                }
            }
            uint lo = (uint)f2b(v.x) | ((uint)f2b(v.y) << 16);
            uint hi = (uint)f2b(v.z) | ((uint)f2b(v.w) << 16);
            *(uint2*)&pin[li * K1_STR + q * 4] = make_uint2(lo, hi);
        }
    }
    // stage xe -> pin[li][64..67]
    for (int li = t; li < K1_ROWS; li += 256) {
        int l = l0 - 1 + li;
        float4 v = make_float4(0.f, 0.f, 0.f, 0.f);
        if (l >= 0 && l < LL)
            v = *(const float4*)&xe[(size_t)(be * LL + l) * 4];
        uint lo = (uint)f2b(v.x) | ((uint)f2b(v.y) << 16);
        uint hi = (uint)f2b(v.z) | ((uint)f2b(v.w) << 16);
        *(uint2*)&pin[li * K1_STR + 64] = make_uint2(lo, hi);
    }
    // zero pin[li][68..95]
    {
        uint* pz = (uint*)pin;
        for (int pos = t; pos < K1_ROWS * 14; pos += 256) {
            int li = pos / 14, j = pos - li * 14;
            pz[li * 52 + 34 + j] = 0u;
        }
    }
    __syncthreads();

    const int lane = t & 63;
    const int w = t >> 6;
    const int och = w & 1, lh = w >> 1;
    const int m = lane & 15, h = lane >> 4;

    // A fragments: weights, 2 oc-tiles x (3 taps x 3 chunks)
    short8 fa[2][9];
#pragma unroll
    for (int mi = 0; mi < 2; ++mi)
#pragma unroll
        for (int k = 0; k < 3; ++k)
#pragma unroll
            for (int c = 0; c < 3; ++c)
                fa[mi][k * 3 + c] = *(const short8*)&w1b[
                    (size_t)(k * 64 + och * 32 + mi * 16 + m) * 96 + c * 32 + h * 8];

    f32x4 acc[2][4] = {};
#pragma unroll
    for (int tt = 0; tt < 4; ++tt) {
        const int rowbase = lh * 64 + tt * 16 + m;
#pragma unroll
        for (int k = 0; k < 3; ++k) {
#pragma unroll
            for (int c = 0; c < 3; ++c) {
                short8 fb = *(const short8*)&pin[(rowbase + k) * K1_STR + c * 32 + h * 8];
                acc[0][tt] = __builtin_amdgcn_mfma_f32_16x16x32_bf16(fa[0][k * 3 + c], fb, acc[0][tt], 0, 0, 0);
                acc[1][tt] = __builtin_amdgcn_mfma_f32_16x16x32_bf16(fa[1][k * 3 + c], fb, acc[1][tt], 0, 0, 0);
            }
        }
    }

    // epilogue: bias, packed bf16 store to h1[n][l][oc], group sums
#pragma unroll
    for (int mi = 0; mi < 2; ++mi) {
        float bias[4];
#pragma unroll
        for (int r = 0; r < 4; ++r)
            bias[r] = b1[och * 32 + mi * 16 + h * 4 + r];
        float s1 = 0.f, s2 = 0.f;
#pragma unroll
        for (int tt = 0; tt < 4; ++tt) {
            int l = l0 + lh * 64 + tt * 16 + m;
            float v0 = acc[mi][tt][0] + bias[0];
            float v1 = acc[mi][tt][1] + bias[1];
            float v2 = acc[mi][tt][2] + bias[2];
            float v3 = acc[mi][tt][3] + bias[3];
            s1 += v0 + v1 + v2 + v3;
            s2 += v0 * v0 + v1 * v1 + v2 * v2 + v3 * v3;
            uint2 pk;
            pk.x = (uint)f2b(v0) | ((uint)f2b(v1) << 16);
            pk.y = (uint)f2b(v2) | ((uint)f2b(v3) << 16);
            *(uint2*)&h1[((size_t)n * LL + l) * 64 + och * 32 + mi * 16 + h * 4] = pk;
        }
#pragma unroll
        for (int off = 32; off > 0; off >>= 1) {
            s1 += __shfl_down(s1, off, 64);
            s2 += __shfl_down(s2, off, 64);
        }
        if (lane == 0) {
            int gidx = och * 2 + mi;   // == GN group (oc>>4)
            part[(((size_t)n * 4 + gidx) * 64 + lt * 2 + lh) * 2 + 0] = s1;
            part[(((size_t)n * 4 + gidx) * 64 + lt * 2 + lh) * 2 + 1] = s2;
        }
    }
}

// ---------------- K3: stats + GN+GELU -> conv2(MFMA)+GELU -> conv3 -> tanh*10
// tile: 126 outputs, 128 h2 positions (j=0..127 <-> l=l0-1+j)
#define K3_ROWS 130
#define K3_STR  72    // ushorts per row (144 B = 9 x 16B)
#define H2_STR  132
__global__ __launch_bounds__(256) void k3_rest(const ushort* __restrict__ h1,
    const float* __restrict__ part, const float* __restrict__ gn_g,
    const float* __restrict__ gn_b, const float* __restrict__ b2,
    const ushort* __restrict__ w2b, const float* __restrict__ w3,
    float* __restrict__ offs)
{
    __shared__ ushort p2[K3_ROWS * K3_STR];   // 18720 B
    __shared__ float h2s[OC2 * H2_STR];       // 16896 B
    __shared__ float sstats[8];
    const int n = blockIdx.y, lt = blockIdx.x;
    const int l0 = lt * 126;
    const int t = threadIdx.x;
    const int lane = t & 63;
    const int w = t >> 6;

    // per-block stats: wave w reduces GN group w over part (L2-hot, 2 KB)
    {
        float2 p = *(const float2*)&part[(((size_t)n * 4 + w) * 64 + lane) * 2];
        float s1 = p.x, s2 = p.y;
#pragma unroll
        for (int off = 32; off > 0; off >>= 1) {
            s1 += __shfl_down(s1, off, 64);
            s2 += __shfl_down(s2, off, 64);
        }
        if (lane == 0) {
            float mean = s1 * (1.0f / 65536.0f);
            float var  = s2 * (1.0f / 65536.0f) - mean * mean;
            sstats[w * 2 + 0] = mean;
            sstats[w * 2 + 1] = 1.0f / sqrtf(var + 1e-5f);
        }
    }
    __syncthreads();

    // per-thread GN affine for its 8 channels (q constant per thread)
    const int q = t & 7;
    float Af[8], Bf[8];
    {
        int gi = q >> 1;                       // 8 consecutive ch share a group
        float mean = sstats[gi * 2], istd = sstats[gi * 2 + 1];
#pragma unroll
        for (int j = 0; j < 8; ++j) {
            float ga = gn_g[q * 8 + j];
            Af[j] = istd * ga;
            Bf[j] = gn_b[q * 8 + j] - mean * Af[j];
        }
    }

    // stage GELU(GN(h1)) -> p2[li][ch]; li <-> l = l0-2+li, zero outside
    for (int pos = t; pos < K3_ROWS * 8; pos += 256) {
        int li = pos >> 3;
        int l = l0 - 2 + li;
        uint4 o = make_uint4(0u, 0u, 0u, 0u);
        if (l >= 0 && l < LL) {
            uint4 u = *(const uint4*)&h1[((size_t)n * LL + l) * 64 + q * 8];
            const ushort* us = (const ushort*)&u;
            ushort vb[8];
#pragma unroll
            for (int j = 0; j < 8; ++j) {
                float xn = fmaf(b2f(us[j]), Af[j], Bf[j]);
                vb[j] = f2b(fast_gelu(xn));
            }
            o.x = (uint)vb[0] | ((uint)vb[1] << 16);
            o.y = (uint)vb[2] | ((uint)vb[3] << 16);
            o.z = (uint)vb[4] | ((uint)vb[5] << 16);
            o.w = (uint)vb[6] | ((uint)vb[7] << 16);
        }
        *(uint4*)&p2[li * K3_STR + q * 8] = o;
    }
    __syncthreads();

    const int m = lane & 15, h = lane >> 4;

    // A fragments: 2 oc-tiles x (3 taps x 2 chunks)
    short8 fa[2][6];
#pragma unroll
    for (int mi = 0; mi < 2; ++mi)
#pragma unroll
        for (int k = 0; k < 3; ++k)
#pragma unroll
            for (int c = 0; c < 2; ++c)
                fa[mi][k * 2 + c] = *(const short8*)&w2b[
                    (size_t)(k * 32 + mi * 16 + m) * 64 + c * 32 + h * 8];

    float bias2[2][4];
#pragma unroll
    for (int mi = 0; mi < 2; ++mi)
#pragma unroll
        for (int r = 0; r < 4; ++r)
            bias2[mi][r] = b2[mi * 16 + h * 4 + r];

    f32x4 acc[2][2] = {};
#pragma unroll
    for (int u = 0; u < 2; ++u) {
        const int jb = (w * 2 + u) * 16 + m;     // col j
#pragma unroll
        for (int k = 0; k < 3; ++k) {
#pragma unroll
            for (int c = 0; c < 2; ++c) {
                short8 fb = *(const short8*)&p2[(jb + k) * K3_STR + c * 32 + h * 8];
                acc[0][u] = __builtin_amdgcn_mfma_f32_16x16x32_bf16(fa[0][k * 2 + c], fb, acc[0][u], 0, 0, 0);
                acc[1][u] = __builtin_amdgcn_mfma_f32_16x16x32_bf16(fa[1][k * 2 + c], fb, acc[1][u], 0, 0, 0);
            }
        }
    }
    // h2 = GELU(acc + b2) -> h2s[oc][j], zero for l outside
#pragma unroll
    for (int mi = 0; mi < 2; ++mi) {
#pragma unroll
        for (int u = 0; u < 2; ++u) {
            int j = (w * 2 + u) * 16 + m;
            int lj = l0 - 1 + j;
#pragma unroll
            for (int r = 0; r < 4; ++r) {
                int oc = mi * 16 + h * 4 + r;
                float v = 0.f;
                if (lj >= 0 && lj < LL)
                    v = fast_gelu(acc[mi][u][r] + bias2[mi][r]);
                h2s[oc * H2_STR + j] = v;
            }
        }
    }
    __syncthreads();

    // conv3 + tanh*10
    for (int qq = t; qq < 126; qq += 256) {
        int l = l0 + qq;
        if (l >= LL) break;
        float a = 0.f;
#pragma unroll
        for (int ic = 0; ic < OC2; ++ic) {
            a = fmaf(w3[ic * 3 + 0], h2s[ic * H2_STR + qq],     a);
            a = fmaf(w3[ic * 3 + 1], h2s[ic * H2_STR + qq + 1], a);
            a = fmaf(w3[ic * 3 + 2], h2s[ic * H2_STR + qq + 2], a);
        }
        offs[(size_t)n * LL + l] = fast_tanh(a) * 10.0f;
    }
}

extern "C" void kernel_launch(void* const* d_in, const int* in_sizes, int n_in,
                              void* d_out, int out_size, void* d_ws, size_t ws_size,
                              hipStream_t stream)
{
    const float* x    = (const float*)d_in[0];
    const float* xext = (const float*)d_in[1];
    const float* w1   = (const float*)d_in[2];
    const float* b1   = (const float*)d_in[3];
    const float* gng  = (const float*)d_in[4];
    const float* gnb  = (const float*)d_in[5];
    const float* w2   = (const float*)d_in[6];
    const float* b2   = (const float*)d_in[7];
    const float* w3   = (const float*)d_in[8];
    const float* gate = (const float*)d_in[9];

    float* out  = (float*)d_out;
    float* offs = out + (size_t)BB * LL * CC;        // 33,554,432

    char* ws = (char*)d_ws;
    ushort* h1  = (ushort*)(ws);                     // 67,108,864 B
    float* part = (float*)(ws + 67108864);           // 262,144 B
    ushort* w1b = (ushort*)(ws + 67371008);          // 36,864 B
    ushort* w2b = (ushort*)(ws + 67407872);          // 12,288 B
    float* corr = (float*)(ws + 67420160);           // 32,768 B

    k_prep<<<128, 256, 0, stream>>>(x, w1, w2, gate, w1b, w2b, corr);
    dim3 g1(32, NG);
    k1_conv1<<<g1, 256, 0, stream>>>(x, xext, b1, w1b, corr, h1, part, out);
    dim3 g3(33, NG);
    k3_rest<<<g3, 256, 0, stream>>>(h1, part, gng, gnb, b2, w2b, w3, offs);
}